// Round 6
// baseline (17.710 us; speedup 1.0000x reference)
//
#include <hip/hip_runtime.h>
#include <hip/hip_bf16.h>

// Problem constants
constexpr int Bv   = 4;
constexpr int Lv   = 4096;
constexpr int Dv   = 128;
constexpr int Av   = 16;
constexpr int Wwin = 2*Av + 1;  // 33
constexpr int OUTv = 2;
constexpr int HIDv = 24;
constexpr int NROWS = Bv * Lv;  // 16384

constexpr int TILE  = 32;           // output rows per block
constexpr int SROWS = TILE + 2*Av;  // 64 staged rows
constexpr int NBLK  = NROWS / TILE; // 512
constexpr int NXCD  = 8;

typedef __attribute__((ext_vector_type(8))) short short8;   // 8 bf16 (4 VGPR)
typedef __attribute__((ext_vector_type(4))) unsigned uint4v;
typedef __attribute__((ext_vector_type(4))) float f32x4;    // MFMA acc

// Compiler-native bf16 conversion (emits v_cvt_pk_bf16_f32; m240: faster than
// hand-rolled integer RNE). Union punning: __hip_bfloat162 isn't trivially
// copyable so __builtin_bit_cast is rejected.
__device__ __forceinline__ unsigned pk2(float lo, float hi) {
    union { __hip_bfloat162 h; unsigned u; } cvt;
    cvt.h = __float22bfloat162_rn(make_float2(lo, hi));
    return cvt.u;
}
__device__ __forceinline__ short bf1(float f) {
    union { __hip_bfloat16 h; short s; } cvt;
    cvt.h = __float2bfloat16(f);
    return cvt.s;
}

// ---------------------------------------------------------------------------
// Single fused kernel: per block = 32 output rows (+16 halo each side).
// grid 512, 256 threads (4 waves), LDS ~36.2 KB
__global__ __launch_bounds__(256) void k_all(const float* __restrict__ x,
                                             const float* __restrict__ W1,
                                             const float* __restrict__ b1,
                                             const float* __restrict__ Wv,
                                             const float* __restrict__ fc2,
                                             const float* __restrict__ fc2b,
                                             const float* __restrict__ fc3w,
                                             const float* __restrict__ fc3b,
                                             float* __restrict__ out,
                                             float* __restrict__ aout) {
    __shared__ short sA[SROWS][136];    // x then h1, bf16 (17408 B)
    __shared__ short sWfT[32][136];     // Wf^T bf16      (8704 B)
    __shared__ float smv[SROWS][25];    // m, f32         (6400 B)
    __shared__ float sh2[TILE][25];     // h2, f32        (3200 B)
    __shared__ float sb1[Dv];           // 512 B

    const int t = threadIdx.x;
    // XCD-aware bijective swizzle (NBLK % NXCD == 0): XCD k owns 64 contiguous
    // row-tiles -> halo re-reads + weight broadcasts are XCD-L2-local.
    const int bid = blockIdx.x;
    const int blk = (bid & (NXCD-1)) * (NBLK/NXCD) + (bid >> 3);

    const int g0 = blk * TILE;               // global output row base
    const int bb = g0 >> 12;                 // batch index
    const int l0 = g0 & (Lv - 1);            // in-batch row base
    const int lane = t & 63, w = t >> 6;
    const int arow = lane & 15;
    const int kgrp = (lane >> 4) * 8;
    const int crow = (lane >> 4) * 4;

    // ---- phase 1: stage x tile (rows l0-16 .. l0+47), bf16, zero outside [0,Lv)
    for (int i = t; i < SROWS*32; i += 256) {
        const int r = i >> 5, c4 = i & 31;
        const int l = l0 - Av + r;
        uint2 o = make_uint2(0u, 0u);
        if (l >= 0 && l < Lv) {
            const float4 v = *(const float4*)&x[((size_t)bb*Lv + l)*Dv + c4*4];
            o.x = pk2(v.x, v.y);
            o.y = pk2(v.z, v.w);
        }
        *(uint2*)&sA[r][c4*4] = o;
    }
    if (t < Dv) sb1[t] = b1[t];

    // ---- attention weights = 1.0 (independent; overlaps with loads)
    {
        float4* a4 = (float4*)aout;
        const float4 one4 = {1.f, 1.f, 1.f, 1.f};
        for (int i = t; i < 264; i += 256)       // 512 blocks x 264 = 135168 float4
            a4[(size_t)blk*264 + i] = one4;
    }

    // ---- phase 2: Wf = Wv @ fc2 via MFMA (per-block redundant, L2-resident)
    {
        f32x4 accW[2][2];
#pragma unroll
        for (int a = 0; a < 2; ++a) { accW[a][0] = (f32x4){0,0,0,0}; accW[a][1] = (f32x4){0,0,0,0}; }
#pragma unroll
        for (int kb = 0; kb < 4; ++kb) {
            const int kof = kb*32 + kgrp;
            short8 bW[2];
#pragma unroll
            for (int nf = 0; nf < 2; ++nf) {
                const int n = nf*16 + arow;
                float f[8];
#pragma unroll
                for (int j = 0; j < 8; ++j)
                    f[j] = (n < HIDv) ? fc2[(size_t)(kof + j)*HIDv + n] : 0.f;
                uint4v u = {pk2(f[0],f[1]), pk2(f[2],f[3]), pk2(f[4],f[5]), pk2(f[6],f[7])};
                bW[nf] = __builtin_bit_cast(short8, u);
            }
#pragma unroll
            for (int mf2 = 0; mf2 < 2; ++mf2) {
                const int m = (w*2 + mf2)*16 + arow;
                const float4 v0 = *(const float4*)&Wv[(size_t)m*Dv + kof];
                const float4 v1 = *(const float4*)&Wv[(size_t)m*Dv + kof + 4];
                uint4v u = {pk2(v0.x,v0.y), pk2(v0.z,v0.w), pk2(v1.x,v1.y), pk2(v1.z,v1.w)};
                const short8 aW = __builtin_bit_cast(short8, u);
                accW[mf2][0] = __builtin_amdgcn_mfma_f32_16x16x32_bf16(aW, bW[0], accW[mf2][0], 0, 0, 0);
                accW[mf2][1] = __builtin_amdgcn_mfma_f32_16x16x32_bf16(aW, bW[1], accW[mf2][1], 0, 0, 0);
            }
        }
        // write Wf^T: C-frag val = Wf[(w*2+mf2)*16 + crow + r][nf*16 + arow]
#pragma unroll
        for (int mf2 = 0; mf2 < 2; ++mf2) {
#pragma unroll
            for (int nf = 0; nf < 2; ++nf) {
                const int n = nf*16 + arow;
                const int m = (w*2 + mf2)*16 + crow;
                uint2 o;
                o.x = pk2(accW[mf2][nf][0], accW[mf2][nf][1]);
                o.y = pk2(accW[mf2][nf][2], accW[mf2][nf][3]);
                *(uint2*)&sWfT[n][m] = o;
            }
        }
    }
    __syncthreads();   // publish sA (x) + sWfT

    // ---- phase 3: GEMM1  h1(64x128) = x @ W1 ; wave w owns cols [w*32, w*32+32)
    const int ncol0 = w * 32;
    f32x4 acc[4][2];
#pragma unroll
    for (int mf = 0; mf < 4; ++mf) { acc[mf][0] = (f32x4){0,0,0,0}; acc[mf][1] = (f32x4){0,0,0,0}; }

#pragma unroll
    for (int kb = 0; kb < 4; ++kb) {
        const int kof = kb*32 + kgrp;
        // B-frags on the fly from fp32 W1 (XCD-L2-resident)
        short8 bf0, bf1v;
        {
            const int n0 = ncol0 + arow, n1 = ncol0 + 16 + arow;
            float a0[8], a1[8];
#pragma unroll
            for (int j = 0; j < 8; ++j) {
                a0[j] = W1[(size_t)(kof + j)*Dv + n0];
                a1[j] = W1[(size_t)(kof + j)*Dv + n1];
            }
            uint4v u0 = {pk2(a0[0],a0[1]), pk2(a0[2],a0[3]), pk2(a0[4],a0[5]), pk2(a0[6],a0[7])};
            uint4v u1 = {pk2(a1[0],a1[1]), pk2(a1[2],a1[3]), pk2(a1[4],a1[5]), pk2(a1[6],a1[7])};
            bf0  = __builtin_bit_cast(short8, u0);
            bf1v = __builtin_bit_cast(short8, u1);
        }
#pragma unroll
        for (int mf = 0; mf < 4; ++mf) {
            const short8 af = *(const short8*)&sA[mf*16 + arow][kof];
            acc[mf][0] = __builtin_amdgcn_mfma_f32_16x16x32_bf16(af, bf0,  acc[mf][0], 0, 0, 0);
            acc[mf][1] = __builtin_amdgcn_mfma_f32_16x16x32_bf16(af, bf1v, acc[mf][1], 0, 0, 0);
        }
    }
    __syncthreads();   // all waves done reading sA (x)

    // ---- phase 4: h1 = relu(acc + b1) -> sA as bf16
    // C/D layout: col = lane&15, row = (lane>>4)*4 + reg   [m89-verified]
#pragma unroll
    for (int mf = 0; mf < 4; ++mf) {
#pragma unroll
        for (int nf = 0; nf < 2; ++nf) {
            const int col  = ncol0 + nf*16 + arow;
            const float bias = sb1[col];
#pragma unroll
            for (int r = 0; r < 4; ++r) {
                float h = acc[mf][nf][r] + bias;
                h = h > 0.f ? h : 0.f;
                sA[mf*16 + crow + r][col] = bf1(h);
            }
        }
    }
    __syncthreads();

    // ---- phase 5: GEMM2  m(64x24) = h1 @ Wf (128x24 padded 32); 2 pairs/wave
    f32x4 acc2[2];
    acc2[0] = (f32x4){0,0,0,0};
    acc2[1] = (f32x4){0,0,0,0};
#pragma unroll
    for (int pp = 0; pp < 2; ++pp) {
        const int p = w*2 + pp, mf = p >> 1, nf = p & 1;
#pragma unroll
        for (int kb = 0; kb < 4; ++kb) {
            const int kof = kb*32 + kgrp;
            const short8 af = *(const short8*)&sA[mf*16 + arow][kof];
            const short8 bf = *(const short8*)&sWfT[nf*16 + arow][kof];
            acc2[pp] = __builtin_amdgcn_mfma_f32_16x16x32_bf16(af, bf, acc2[pp], 0, 0, 0);
        }
    }
    // write m -> smv (zero rows whose in-batch index is out of range)
#pragma unroll
    for (int pp = 0; pp < 2; ++pp) {
        const int p = w*2 + pp, mf = p >> 1, nf = p & 1;
        const int col = nf*16 + arow;
        if (col < HIDv) {
#pragma unroll
            for (int r = 0; r < 4; ++r) {
                const int row = mf*16 + crow + r;
                const int l = l0 - Av + row;
                smv[row][col] = (l >= 0 && l < Lv) ? acc2[pp][r] : 0.f;
            }
        }
    }
    __syncthreads();

    // ---- phase 6: sliding 33-sum + fc2_b + relu -> sh2 (running-sum, 8-row groups)
    if (t < 96) {
        const int c = t % 24, rg = t / 24;
        const int rb = rg * 8;
        float s = 0.f;
#pragma unroll
        for (int ww = 0; ww < Wwin; ++ww) s += smv[rb + ww][c];
        const float bias = fc2b[c];
#pragma unroll
        for (int r2 = 0; r2 < 8; ++r2) {
            const int rr = rb + r2;
            const float h = s + bias;
            sh2[rr][c] = h > 0.f ? h : 0.f;
            if (r2 < 7) s += smv[rr + Wwin][c] - smv[rr][c];
        }
    }
    __syncthreads();

    // ---- phase 7: fc3 (32x24)@(24x2) + b -> out
    if (t < TILE*OUTv) {
        const int r = t >> 1, oc = t & 1;
        float a = fc3b[oc];
#pragma unroll
        for (int c = 0; c < HIDv; ++c)
            a = fmaf(sh2[r][c], fc3w[c*OUTv + oc], a);
        out[(size_t)(g0 + r)*OUTv + oc] = a;
    }
}

// ---------------------------------------------------------------------------
extern "C" void kernel_launch(void* const* d_in, const int* in_sizes, int n_in,
                              void* d_out, int out_size, void* d_ws, size_t ws_size,
                              hipStream_t stream) {
    const float* x     = (const float*)d_in[0];
    const float* fc1_w = (const float*)d_in[1];
    const float* fc1_b = (const float*)d_in[2];
    // d_in[3] = Wq_w, d_in[4] = Wk_w : dead (softmax over singleton axis)
    const float* Wv_w  = (const float*)d_in[5];
    const float* fc2_w = (const float*)d_in[6];
    const float* fc2_b = (const float*)d_in[7];
    const float* fc3_w = (const float*)d_in[8];
    const float* fc3_b = (const float*)d_in[9];

    float* out  = (float*)d_out;                    // (B,L,2)    32768 floats
    float* aout = (float*)d_out + NROWS * OUTv;     // (B,L,1,33) 540672 floats

    k_all<<<dim3(NBLK), dim3(256), 0, stream>>>(x, fc1_w, fc1_b, Wv_w, fc2_w,
                                                fc2_b, fc3_w, fc3_b, out, aout);
}

// Round 7
// 16.959 us; speedup vs baseline: 1.0443x; 1.0443x over previous
//
#include <hip/hip_runtime.h>

// Problem constants
constexpr int Bv   = 4;
constexpr int Lv   = 4096;
constexpr int Dv   = 128;
constexpr int Av   = 16;
constexpr int Wwin = 2*Av + 1;  // 33
constexpr int OUTv = 2;
constexpr int HIDv = 24;
constexpr int NROWS = Bv * Lv;  // 16384

constexpr int TILE  = 32;           // output rows per block
constexpr int SROWS = TILE + 2*Av;  // 64 staged rows
constexpr int NBLK  = NROWS / TILE; // 512

typedef __attribute__((ext_vector_type(8))) short short8;   // 8 bf16 (4 VGPR)
typedef __attribute__((ext_vector_type(4))) short short4v;  // 4 bf16 (8B)
typedef __attribute__((ext_vector_type(4))) float f32x4;    // MFMA acc

__device__ __forceinline__ short f2bf(float f) {  // RNE fp32->bf16 (3 VALU)
    unsigned u = __builtin_bit_cast(unsigned, f);
    u += 0x7FFFu + ((u >> 16) & 1u);
    return (short)(u >> 16);
}

// ---------------------------------------------------------------------------
// Single fused kernel: per block = 32 output rows (+16 halo each side).
//   Wf = Wv@fc2 per-block via MFMA (redundant; weights L2-resident)
//   h1 = relu(x@W1+b1) via MFMA, W1 B-frags PREFETCHED to regs pre-barrier
//   m  = h1@Wf via MFMA; sliding 33-sum + fc2_b + relu; fc3 -> out
//   a-output = 1.0 (softmax over size-1 axis)
// grid 512, 256 threads (4 waves), LDS ~52.4 KB -> 2 blocks/CU
__global__ __launch_bounds__(256) void k_all(const float* __restrict__ x,
                                             const float* __restrict__ W1,
                                             const float* __restrict__ b1,
                                             const float* __restrict__ Wv,
                                             const float* __restrict__ fc2,
                                             const float* __restrict__ fc2b,
                                             const float* __restrict__ fc3w,
                                             const float* __restrict__ fc3b,
                                             float* __restrict__ out,
                                             float* __restrict__ aout) {
    __shared__ short sA[SROWS][136];    // x tile, bf16   (17408 B)
    __shared__ short sH[SROWS][136];    // h1, bf16       (17408 B)
    __shared__ short sWfT[32][136];     // Wf^T bf16      (8704 B)
    __shared__ float smv[SROWS][25];    // m, f32         (6400 B)
    __shared__ float sh2[TILE][25];     // h2, f32        (3200 B)
    __shared__ float sb1[Dv];           // 512 B

    const int t = threadIdx.x, blk = blockIdx.x;
    const int g0 = blk * TILE;               // global output row base
    const int bb = g0 >> 12;                 // batch index
    const int l0 = g0 & (Lv - 1);            // in-batch row base
    const int lane = t & 63, w = t >> 6;
    const int arow = lane & 15;
    const int kgrp = (lane >> 4) * 8;
    const int crow = (lane >> 4) * 4;
    const int ncol0 = w * 32;                // GEMM1 column range of this wave

    // ---- phase 1: stage x tile (rows l0-16 .. l0+47), bf16, zero outside [0,Lv)
    for (int i = t; i < SROWS*32; i += 256) {
        const int r = i >> 5, c4 = i & 31;
        const int l = l0 - Av + r;
        short4v o = {0, 0, 0, 0};
        if (l >= 0 && l < Lv) {
            const float4 v = *(const float4*)&x[((size_t)bb*Lv + l)*Dv + c4*4];
            o[0] = f2bf(v.x); o[1] = f2bf(v.y); o[2] = f2bf(v.z); o[3] = f2bf(v.w);
        }
        *(short4v*)&sA[r][c4*4] = o;
    }
    if (t < Dv) sb1[t] = b1[t];

    // ---- attention weights = 1.0 (independent; overlaps with loads)
    {
        float4* a4 = (float4*)aout;
        const float4 one4 = {1.f, 1.f, 1.f, 1.f};
        for (int i = t; i < 264; i += 256)       // 512 blocks x 264 = 135168 float4
            a4[(size_t)blk*264 + i] = one4;
    }

    // ---- prefetch GEMM1 B-frags from fp32 W1 into registers (pre-barrier:
    //      loads + cvt overlap x-staging and the Wf phase; after barrier 1
    //      GEMM1 is pure ds_read+MFMA)
    short8 pb0[4], pb1[4];
    {
        const int n0 = ncol0 + arow, n1 = ncol0 + 16 + arow;
#pragma unroll
        for (int kb = 0; kb < 4; ++kb) {
            const int kof = kb*32 + kgrp;
            float a0[8], a1[8];
#pragma unroll
            for (int j = 0; j < 8; ++j) {
                a0[j] = W1[(size_t)(kof + j)*Dv + n0];
                a1[j] = W1[(size_t)(kof + j)*Dv + n1];
            }
            short8 b0, b1v;
#pragma unroll
            for (int j = 0; j < 8; ++j) { b0[j] = f2bf(a0[j]); b1v[j] = f2bf(a1[j]); }
            pb0[kb] = b0; pb1[kb] = b1v;
        }
    }

    // ---- phase 2: Wf = Wv @ fc2 via MFMA (per-block redundant, L2-resident)
    {
        f32x4 accW[2][2];
#pragma unroll
        for (int a = 0; a < 2; ++a) { accW[a][0] = (f32x4){0,0,0,0}; accW[a][1] = (f32x4){0,0,0,0}; }
#pragma unroll
        for (int kb = 0; kb < 4; ++kb) {
            const int kof = kb*32 + kgrp;
            short8 bW[2];
#pragma unroll
            for (int nf = 0; nf < 2; ++nf) {
                const int n = nf*16 + arow;
#pragma unroll
                for (int j = 0; j < 8; ++j) {
                    const float v = (n < HIDv) ? fc2[(size_t)(kof + j)*HIDv + n] : 0.f;
                    bW[nf][j] = f2bf(v);
                }
            }
#pragma unroll
            for (int mf2 = 0; mf2 < 2; ++mf2) {
                const int m = (w*2 + mf2)*16 + arow;
                const float4 v0 = *(const float4*)&Wv[(size_t)m*Dv + kof];
                const float4 v1 = *(const float4*)&Wv[(size_t)m*Dv + kof + 4];
                short8 aW;
                aW[0] = f2bf(v0.x); aW[1] = f2bf(v0.y); aW[2] = f2bf(v0.z); aW[3] = f2bf(v0.w);
                aW[4] = f2bf(v1.x); aW[5] = f2bf(v1.y); aW[6] = f2bf(v1.z); aW[7] = f2bf(v1.w);
                accW[mf2][0] = __builtin_amdgcn_mfma_f32_16x16x32_bf16(aW, bW[0], accW[mf2][0], 0, 0, 0);
                accW[mf2][1] = __builtin_amdgcn_mfma_f32_16x16x32_bf16(aW, bW[1], accW[mf2][1], 0, 0, 0);
            }
        }
        // write Wf^T: C-frag val = Wf[(w*2+mf2)*16 + crow + r][nf*16 + arow]
#pragma unroll
        for (int mf2 = 0; mf2 < 2; ++mf2) {
#pragma unroll
            for (int nf = 0; nf < 2; ++nf) {
                const int n = nf*16 + arow;
                const int m = (w*2 + mf2)*16 + crow;
                short4v o;
                o[0] = f2bf(accW[mf2][nf][0]);
                o[1] = f2bf(accW[mf2][nf][1]);
                o[2] = f2bf(accW[mf2][nf][2]);
                o[3] = f2bf(accW[mf2][nf][3]);
                *(short4v*)&sWfT[n][m] = o;
            }
        }
    }
    __syncthreads();   // B1: publish sA (x) + sWfT

    // ---- phase 3: GEMM1 h1(64x128) = x @ W1, cols [ncol0, ncol0+32);
    //      pure ds_read + MFMA (B-frags already in regs); h1 -> sH (no extra barrier)
    {
        f32x4 acc[4][2];
#pragma unroll
        for (int mf = 0; mf < 4; ++mf) { acc[mf][0] = (f32x4){0,0,0,0}; acc[mf][1] = (f32x4){0,0,0,0}; }

#pragma unroll
        for (int kb = 0; kb < 4; ++kb) {
            const int kof = kb*32 + kgrp;
#pragma unroll
            for (int mf = 0; mf < 4; ++mf) {
                const short8 af = *(const short8*)&sA[mf*16 + arow][kof];
                acc[mf][0] = __builtin_amdgcn_mfma_f32_16x16x32_bf16(af, pb0[kb], acc[mf][0], 0, 0, 0);
                acc[mf][1] = __builtin_amdgcn_mfma_f32_16x16x32_bf16(af, pb1[kb], acc[mf][1], 0, 0, 0);
            }
        }

        // h1 = relu(acc + b1) -> sH as bf16
        // C/D layout: col = lane&15, row = (lane>>4)*4 + reg   [m89-verified]
#pragma unroll
        for (int mf = 0; mf < 4; ++mf) {
#pragma unroll
            for (int nf = 0; nf < 2; ++nf) {
                const int col  = ncol0 + nf*16 + arow;
                const float bias = sb1[col];
#pragma unroll
                for (int r = 0; r < 4; ++r) {
                    float h = acc[mf][nf][r] + bias;
                    h = h > 0.f ? h : 0.f;
                    sH[mf*16 + crow + r][col] = f2bf(h);
                }
            }
        }
    }
    __syncthreads();   // B2: publish h1

    // ---- phase 5: GEMM2  m(64x24) = h1 @ Wf (128x24 padded 32); 2 pairs/wave
    f32x4 acc2[2];
    acc2[0] = (f32x4){0,0,0,0};
    acc2[1] = (f32x4){0,0,0,0};
#pragma unroll
    for (int pp = 0; pp < 2; ++pp) {
        const int p = w*2 + pp, mf = p >> 1, nf = p & 1;
#pragma unroll
        for (int kb = 0; kb < 4; ++kb) {
            const int kof = kb*32 + kgrp;
            const short8 af = *(const short8*)&sH[mf*16 + arow][kof];
            const short8 bf = *(const short8*)&sWfT[nf*16 + arow][kof];
            acc2[pp] = __builtin_amdgcn_mfma_f32_16x16x32_bf16(af, bf, acc2[pp], 0, 0, 0);
        }
    }
    // write m -> smv (zero rows whose in-batch index is out of range)
#pragma unroll
    for (int pp = 0; pp < 2; ++pp) {
        const int p = w*2 + pp, mf = p >> 1, nf = p & 1;
        const int col = nf*16 + arow;
        if (col < HIDv) {
#pragma unroll
            for (int r = 0; r < 4; ++r) {
                const int row = mf*16 + crow + r;
                const int l = l0 - Av + row;
                smv[row][col] = (l >= 0 && l < Lv) ? acc2[pp][r] : 0.f;
            }
        }
    }
    __syncthreads();   // B3: publish m

    // ---- phase 6: sliding 33-sum + fc2_b + relu -> sh2 (running-sum, 8-row groups)
    if (t < 96) {
        const int c = t % 24, rg = t / 24;
        const int rb = rg * 8;
        float s = 0.f;
#pragma unroll
        for (int ww = 0; ww < Wwin; ++ww) s += smv[rb + ww][c];
        const float bias = fc2b[c];
#pragma unroll
        for (int r2 = 0; r2 < 8; ++r2) {
            const int rr = rb + r2;
            const float h = s + bias;
            sh2[rr][c] = h > 0.f ? h : 0.f;
            if (r2 < 7) s += smv[rr + Wwin][c] - smv[rr][c];
        }
    }
    __syncthreads();   // B4: publish h2

    // ---- phase 7: fc3 (32x24)@(24x2) + b -> out
    if (t < TILE*OUTv) {
        const int r = t >> 1, oc = t & 1;
        float a = fc3b[oc];
#pragma unroll
        for (int c = 0; c < HIDv; ++c)
            a = fmaf(sh2[r][c], fc3w[c*OUTv + oc], a);
        out[(size_t)(g0 + r)*OUTv + oc] = a;
    }
}

// ---------------------------------------------------------------------------
extern "C" void kernel_launch(void* const* d_in, const int* in_sizes, int n_in,
                              void* d_out, int out_size, void* d_ws, size_t ws_size,
                              hipStream_t stream) {
    const float* x     = (const float*)d_in[0];
    const float* fc1_w = (const float*)d_in[1];
    const float* fc1_b = (const float*)d_in[2];
    // d_in[3] = Wq_w, d_in[4] = Wk_w : dead (softmax over singleton axis)
    const float* Wv_w  = (const float*)d_in[5];
    const float* fc2_w = (const float*)d_in[6];
    const float* fc2_b = (const float*)d_in[7];
    const float* fc3_w = (const float*)d_in[8];
    const float* fc3_b = (const float*)d_in[9];

    float* out  = (float*)d_out;                    // (B,L,2)    32768 floats
    float* aout = (float*)d_out + NROWS * OUTv;     // (B,L,1,33) 540672 floats

    k_all<<<dim3(NBLK), dim3(256), 0, stream>>>(x, fc1_w, fc1_b, Wv_w, fc2_w,
                                                fc2_b, fc3_w, fc3_b, out, aout);
}